// Round 11
// baseline (392.197 us; speedup 1.0000x reference)
//
#include <hip/hip_runtime.h>
#include <hip/hip_bf16.h>
#include <hip/hip_fp16.h>

#define NN 50000
#define NEDGE 800000
#define INDIM 256
#define NH 8
#define ND 32
#define HD 256
#define NT 4
#define NF 16

typedef __attribute__((ext_vector_type(8))) short s16x8;
typedef __attribute__((ext_vector_type(4))) float f32x4;
typedef unsigned short u16;

__device__ __forceinline__ float bf2f(u16 u) {
    return __uint_as_float(((unsigned int)u) << 16);
}
__device__ __forceinline__ u16 f2bf(float f) {
    __hip_bfloat16 h = __float2bfloat16(f);
    return *reinterpret_cast<u16*>(&h);
}
__device__ __forceinline__ u16 f2h(float f) {
    __half h = __float2half(f);
    return *reinterpret_cast<u16*>(&h);
}
__device__ __forceinline__ float h2f(u16 u) {
    __half h = *reinterpret_cast<__half*>(&u);
    return __half2float(h);
}

// ---------------- prep: W transpose->bf16  +  zero cnt/cursor
__global__ __launch_bounds__(256) void prep_kernel(const float* __restrict__ W,
                                                   u16* __restrict__ Wt,
                                                   int* __restrict__ cnt,
                                                   int* __restrict__ cursor)
{
    int idx = blockIdx.x * 256 + threadIdx.x;   // grid = 256 blocks -> 65536
    int k = idx >> 8, c = idx & 255;
    Wt[(size_t)c * 256 + k] = f2bf(W[idx]);
    if (idx < NN) { cnt[idx] = 0; cursor[idx] = 0; }
}

// ---------------- MFMA GEMM (+ dst histogram riding along)
__global__ __launch_bounds__(256) void gemm_mfma(
    const float* __restrict__ feat, const u16* __restrict__ Wt,
    const int* __restrict__ dst, int* __restrict__ cnt,
    u16* __restrict__ fs, int nrows)
{
    const int tid = threadIdx.x;
    {
        int e0 = (blockIdx.x * 256 + tid) * 2;
        if (e0 < NEDGE)     atomicAdd(&cnt[dst[e0]], 1);
        if (e0 + 1 < NEDGE) atomicAdd(&cnt[dst[e0 + 1]], 1);
    }

    __shared__ u16 At[32 * 256];   // 16 KB, swizzled
    const int brow = blockIdx.x * 32;

    #pragma unroll
    for (int it = 0; it < 4; ++it) {
        int fo = it * 2048 + tid * 8;
        int row = fo >> 8, col = fo & 255;
        int grow = brow + row;
        if (grow >= nrows) grow = nrows - 1;
        const float* gp = feat + (size_t)grow * 256 + col;
        float4 x = *reinterpret_cast<const float4*>(gp);
        float4 y = *reinterpret_cast<const float4*>(gp + 4);
        s16x8 v;
        v[0] = (short)f2bf(x.x); v[1] = (short)f2bf(x.y);
        v[2] = (short)f2bf(x.z); v[3] = (short)f2bf(x.w);
        v[4] = (short)f2bf(y.x); v[5] = (short)f2bf(y.y);
        v[6] = (short)f2bf(y.z); v[7] = (short)f2bf(y.w);
        int byte = (col * 2) ^ ((row & 7) << 4);
        *reinterpret_cast<s16x8*>((char*)At + row * 512 + byte) = v;
    }
    __syncthreads();

    const int wave = tid >> 6, lane = tid & 63;
    const int c0 = wave * 64;
    const int rA = lane & 15;
    const int kg = lane >> 4;

    f32x4 acc[2][4] = {};

    for (int k0 = 0; k0 < 256; k0 += 32) {
        const int kk = k0 + kg * 8;
        const int byte = (kk * 2) ^ ((rA & 7) << 4);
        s16x8 a0 = *reinterpret_cast<const s16x8*>((char*)At + rA * 512 + byte);
        s16x8 a1 = *reinterpret_cast<const s16x8*>((char*)At + (16 + rA) * 512 + byte);
        #pragma unroll
        for (int ct = 0; ct < 4; ++ct) {
            s16x8 b = *reinterpret_cast<const s16x8*>(Wt + (size_t)(c0 + ct * 16 + rA) * 256 + kk);
            acc[0][ct] = __builtin_amdgcn_mfma_f32_16x16x32_bf16(a0, b, acc[0][ct], 0, 0, 0);
            acc[1][ct] = __builtin_amdgcn_mfma_f32_16x16x32_bf16(a1, b, acc[1][ct], 0, 0, 0);
        }
    }

    #pragma unroll
    for (int rt = 0; rt < 2; ++rt) {
        #pragma unroll
        for (int r = 0; r < 4; ++r) {
            int row = brow + rt * 16 + kg * 4 + r;
            if (row < nrows) {
                #pragma unroll
                for (int ct = 0; ct < 4; ++ct) {
                    fs[(size_t)row * 256 + c0 + ct * 16 + rA] = f2bf(acc[rt][ct][r]);
                }
            }
        }
    }
}

// ---------------- el/er (f16): [N,H,T] = einsum(fs[n,h,d], attn_{l,r}[h,d,t])
__global__ __launch_bounds__(256) void elr_kernel(
    const u16* __restrict__ fs,
    const float* __restrict__ attn_l, const float* __restrict__ attn_r,
    u16* __restrict__ el, u16* __restrict__ er, int n)
{
    __shared__ float s_al[NH * ND * NT];
    __shared__ float s_ar[NH * ND * NT];
    for (int i = threadIdx.x; i < NH * ND * NT; i += 256) {
        s_al[i] = attn_l[i];
        s_ar[i] = attn_r[i];
    }
    __syncthreads();
    int wv = threadIdx.x >> 6, lane = threadIdx.x & 63;
    int node = blockIdx.x * 4 + wv;
    if (node >= n) return;
    int h = lane >> 3, j0 = (lane & 7) * 4;
    ushort4 u = *reinterpret_cast<const ushort4*>(fs + (size_t)node * HD + lane * 4);
    float f0 = bf2f(u.x), f1 = bf2f(u.y), f2 = bf2f(u.z), f3 = bf2f(u.w);
    const float* al = s_al + h * (ND * NT) + j0 * NT;
    const float* ar = s_ar + h * (ND * NT) + j0 * NT;
    float pl[NT], pr[NT];
    #pragma unroll
    for (int t = 0; t < NT; ++t) {
        pl[t] = f0*al[t] + f1*al[NT + t] + f2*al[2*NT + t] + f3*al[3*NT + t];
        pr[t] = f0*ar[t] + f1*ar[NT + t] + f2*ar[2*NT + t] + f3*ar[3*NT + t];
    }
    #pragma unroll
    for (int d = 1; d < 8; d <<= 1) {
        #pragma unroll
        for (int t = 0; t < NT; ++t) {
            pl[t] += __shfl_xor(pl[t], d);
            pr[t] += __shfl_xor(pr[t], d);
        }
    }
    if ((lane & 7) == 0) {
        ushort4 ol, orr;
        ol.x = f2h(pl[0]); ol.y = f2h(pl[1]); ol.z = f2h(pl[2]); ol.w = f2h(pl[3]);
        orr.x = f2h(pr[0]); orr.y = f2h(pr[1]); orr.z = f2h(pr[2]); orr.w = f2h(pr[3]);
        *reinterpret_cast<ushort4*>(el + (size_t)node * (NH*NT) + h * NT) = ol;
        *reinterpret_cast<ushort4*>(er + (size_t)node * (NH*NT) + h * NT) = orr;
    }
}

// ---------------- CSR scan
__global__ void scan1_kernel(const int* __restrict__ cnt, int* __restrict__ off,
                             int* __restrict__ blksum, int n) {
    __shared__ int sm[256];
    int i = blockIdx.x * 256 + threadIdx.x;
    int v = (i < n) ? cnt[i] : 0;
    sm[threadIdx.x] = v;
    __syncthreads();
    for (int d = 1; d < 256; d <<= 1) {
        int t = (threadIdx.x >= d) ? sm[threadIdx.x - d] : 0;
        __syncthreads();
        sm[threadIdx.x] += t;
        __syncthreads();
    }
    if (i < n) off[i] = sm[threadIdx.x] - v;
    if (threadIdx.x == 255) blksum[blockIdx.x] = sm[255];
}

__global__ void scan2_kernel(int* blksum, int nb) {
    __shared__ int sm[256];
    int v = (threadIdx.x < nb) ? blksum[threadIdx.x] : 0;
    sm[threadIdx.x] = v;
    __syncthreads();
    for (int d = 1; d < 256; d <<= 1) {
        int t = (threadIdx.x >= d) ? sm[threadIdx.x - d] : 0;
        __syncthreads();
        sm[threadIdx.x] += t;
        __syncthreads();
    }
    blksum[threadIdx.x] = sm[threadIdx.x] - v;
}

__global__ void scan3_kernel(int* __restrict__ off, const int* __restrict__ blksum,
                             int n, int ne) {
    int i = blockIdx.x * 256 + threadIdx.x;
    if (i < n) off[i] += blksum[blockIdx.x];
    if (i == 0) off[n] = ne;
}

// ---------------- fillidx: scatter es = int4(e, src, mask packed f16x4). 16B/slot.
__global__ void fillidx_kernel(const int* __restrict__ dst, const int* __restrict__ src,
                               const float* __restrict__ mask,
                               const int* __restrict__ off, int* __restrict__ cursor,
                               int4* __restrict__ es, int ne) {
    int e = blockIdx.x * 256 + threadIdx.x;
    if (e >= ne) return;
    int d = dst[e];
    int s = src[e];
    float4 mk = *reinterpret_cast<const float4*>(mask + (size_t)e * NT);
    int pk01 = (int)f2h(mk.x) | ((int)f2h(mk.y) << 16);
    int pk23 = (int)f2h(mk.z) | ((int)f2h(mk.w) << 16);
    int slot = off[d] + atomicAdd(&cursor[d], 1);
    es[slot] = make_int4(e, s, pk01, pk23);
}

// ---------------- mega agg: in-register edge logits + softmax-normalize + aggregate.
// One wave per dst node. vc-fill: lane (sub,h) computes logit of edge beg+slot*8+sub,
// head h, from es (seq) + e_pro gather + el[src] gather + uniform er[node] + LDS attn_m.
// Phase B identical to round 10 (shfl-distributed w, batched fs row loads).
__global__ __launch_bounds__(256) void agg_kernel(
    const int* __restrict__ off, const int4* __restrict__ es,
    const float* __restrict__ e_pro, const u16* __restrict__ el,
    const u16* __restrict__ er, const float* __restrict__ attn_m,
    const u16* __restrict__ fs, float* __restrict__ out, int n)
{
    __shared__ float4 s_am4[NF][NH];   // [f][h] = attn_m[h][f][0..3]
    for (int i = threadIdx.x; i < NH * NF; i += 256) {
        int hh = i >> 4, f = i & 15;
        const float* p = attn_m + (size_t)hh * (NF * NT) + f * NT;
        s_am4[f][hh] = make_float4(p[0], p[1], p[2], p[3]);
    }
    __syncthreads();

    int wv = threadIdx.x >> 6, lane = threadIdx.x & 63;
    int node = blockIdx.x * 4 + wv;
    if (node >= n) return;
    int beg = off[node], end = off[node + 1];
    int deg = end - beg;

    int h = lane & 7, sub = lane >> 3;
    int h2 = lane >> 3;

    // uniform er[node] rows for head h (vc-fill) and head h2 (deg>64 tail)
    union { uint2 v; u16 u[4]; } erh, erh2;
    erh.v  = *reinterpret_cast<const uint2*>(er + (size_t)node * (NH*NT) + h * NT);
    erh2.v = *reinterpret_cast<const uint2*>(er + (size_t)node * (NH*NT) + h2 * NT);
    float er0 = h2f(erh.u[0]), er1 = h2f(erh.u[1]), er2 = h2f(erh.u[2]), er3 = h2f(erh.u[3]);

    // stage 1: load es for all 8 slots (branch-free; padding -> index 0)
    int4 p[8];
    #pragma unroll
    for (int slot = 0; slot < 8; ++slot) {
        int i = beg + slot * 8 + sub;
        p[slot] = (i < end) ? es[i] : make_int4(0, 0, 0, 0);
    }

    // stage 2: per slot, gather + compute logit -> w
    float vc[8];
    int sc[8];
    #pragma unroll
    for (int slot = 0; slot < 8; ++slot) {
        int i = beg + slot * 8 + sub;
        int e = p[slot].x, s = p[slot].y;
        float mk0 = h2f((u16)(p[slot].z & 0xffff)), mk1 = h2f((u16)((unsigned)p[slot].z >> 16));
        float mk2 = h2f((u16)(p[slot].w & 0xffff)), mk3 = h2f((u16)((unsigned)p[slot].w >> 16));
        const float* ep = e_pro + (size_t)e * NF;
        float4 ep0 = *reinterpret_cast<const float4*>(ep);
        float4 ep1 = *reinterpret_cast<const float4*>(ep + 4);
        float4 ep2 = *reinterpret_cast<const float4*>(ep + 8);
        float4 ep3 = *reinterpret_cast<const float4*>(ep + 12);
        union { uint2 v; u16 u[4]; } lv;
        lv.v = *reinterpret_cast<const uint2*>(el + (size_t)s * (NH*NT) + h * NT);
        float epf[16] = {ep0.x, ep0.y, ep0.z, ep0.w, ep1.x, ep1.y, ep1.z, ep1.w,
                         ep2.x, ep2.y, ep2.z, ep2.w, ep3.x, ep3.y, ep3.z, ep3.w};
        float em = 0.f;
        #pragma unroll
        for (int f = 0; f < NF; ++f) {
            float4 am = s_am4[f][h];
            float amm = mk0*am.x + mk1*am.y + mk2*am.z + mk3*am.w;
            em = fmaf(epf[f], amm, em);
        }
        float left  = mk0*h2f(lv.u[0]) + mk1*h2f(lv.u[1]) + mk2*h2f(lv.u[2]) + mk3*h2f(lv.u[3]);
        float right = mk0*er0 + mk1*er1 + mk2*er2 + mk3*er3;
        float v = (left + right + em) * (1.0f / 3.0f);
        v = v > 0.f ? v : 0.2f * v;
        float w = __expf(v);
        vc[slot] = (i < end) ? w : 0.f;
        sc[slot] = s;
    }

    // phase B: lane owns cols lane*4..+3 for head h2; per-lane sw = full head sum
    const int col = lane * 4;
    float a0 = 0.f, a1 = 0.f, a2 = 0.f, a3 = 0.f, sw = 0.f;
    int deg_ = deg < 64 ? deg : 64;
    int nchunk = (deg_ + 7) >> 3;
    #pragma unroll
    for (int c = 0; c < 8; ++c) {
        if (c >= nchunk) break;               // uniform
        float w8 = vc[c];
        int s8 = sc[c];
        float w[8]; int sn[8];
        #pragma unroll
        for (int q = 0; q < 8; ++q) {
            w[q]  = __shfl(w8, q * 8 + h2);
            sn[q] = __shfl(s8, q * 8 + h2);
        }
        ushort4 u[8];
        #pragma unroll
        for (int q = 0; q < 8; ++q)
            u[q] = *reinterpret_cast<const ushort4*>(fs + (size_t)sn[q] * HD + col);
        #pragma unroll
        for (int q = 0; q < 8; ++q) {         // padding: w=0 -> no-op
            sw += w[q];
            a0 = fmaf(w[q], bf2f(u[q].x), a0);
            a1 = fmaf(w[q], bf2f(u[q].y), a1);
            a2 = fmaf(w[q], bf2f(u[q].z), a2);
            a3 = fmaf(w[q], bf2f(u[q].w), a3);
        }
    }
    // rare deg>64 tail: full logit per edge for head h2
    float er20 = h2f(erh2.u[0]), er21 = h2f(erh2.u[1]), er22 = h2f(erh2.u[2]), er23 = h2f(erh2.u[3]);
    for (int i = beg + 64; i < end; ++i) {
        int4 q = es[i];
        float mk0 = h2f((u16)(q.z & 0xffff)), mk1 = h2f((u16)((unsigned)q.z >> 16));
        float mk2 = h2f((u16)(q.w & 0xffff)), mk3 = h2f((u16)((unsigned)q.w >> 16));
        const float* ep = e_pro + (size_t)q.x * NF;
        float em = 0.f;
        #pragma unroll
        for (int f = 0; f < NF; ++f) {
            float4 am = s_am4[f][h2];
            float amm = mk0*am.x + mk1*am.y + mk2*am.z + mk3*am.w;
            em = fmaf(ep[f], amm, em);
        }
        union { uint2 v; u16 u[4]; } lv;
        lv.v = *reinterpret_cast<const uint2*>(el + (size_t)q.y * (NH*NT) + h2 * NT);
        float left  = mk0*h2f(lv.u[0]) + mk1*h2f(lv.u[1]) + mk2*h2f(lv.u[2]) + mk3*h2f(lv.u[3]);
        float right = mk0*er20 + mk1*er21 + mk2*er22 + mk3*er23;
        float v = (left + right + em) * (1.0f / 3.0f);
        v = v > 0.f ? v : 0.2f * v;
        float w = __expf(v);
        sw += w;
        ushort4 u = *reinterpret_cast<const ushort4*>(fs + (size_t)q.y * HD + col);
        a0 = fmaf(w, bf2f(u.x), a0); a1 = fmaf(w, bf2f(u.y), a1);
        a2 = fmaf(w, bf2f(u.z), a2); a3 = fmaf(w, bf2f(u.w), a3);
    }
    float invS = sw > 0.f ? 1.f / sw : 0.f;
    a0 *= invS; a1 *= invS; a2 *= invS; a3 *= invS;
    *reinterpret_cast<float4*>(&out[(size_t)node * HD + col]) = make_float4(a0, a1, a2, a3);
}

extern "C" void kernel_launch(void* const* d_in, const int* in_sizes, int n_in,
                              void* d_out, int out_size, void* d_ws, size_t ws_size,
                              hipStream_t stream)
{
    const float* feat   = (const float*)d_in[0];
    const float* e_pro  = (const float*)d_in[1];
    const float* mask   = (const float*)d_in[2];
    const float* W_n    = (const float*)d_in[3];
    const float* attn_l = (const float*)d_in[4];
    const float* attn_r = (const float*)d_in[5];
    const float* attn_m = (const float*)d_in[6];
    const int* src      = (const int*)d_in[7];
    const int* dst      = (const int*)d_in[8];
    float* out = (float*)d_out;

    char* ws = (char*)d_ws;
    size_t o = 0;
    auto alloc = [&](size_t bytes) -> void* {
        void* p = (void*)(ws + o);
        o += (bytes + 255) & ~(size_t)255;
        return p;
    };
    u16* fs     = (u16*)alloc((size_t)NN * HD * 2);
    u16* Wt     = (u16*)alloc((size_t)INDIM * HD * 2);
    u16* el     = (u16*)alloc((size_t)NN * NH * NT * 2);
    u16* er     = (u16*)alloc((size_t)NN * NH * NT * 2);
    int4* es    = (int4*)alloc((size_t)NEDGE * 16);
    int* cnt    = (int*)alloc((size_t)NN * 4);
    int* cursor = (int*)alloc((size_t)NN * 4);
    int* offs   = (int*)alloc((size_t)(NN + 1) * 4);
    int* blksum = (int*)alloc(256 * 4);
    (void)ws_size; (void)in_sizes; (void)n_in; (void)out_size;

    dim3 b256(256);
    hipLaunchKernelGGL(prep_kernel, dim3(256), b256, 0, stream, W_n, Wt, cnt, cursor);
    hipLaunchKernelGGL(gemm_mfma, dim3((NN + 31) / 32), b256, 0, stream, feat, Wt, dst, cnt, fs, NN);
    hipLaunchKernelGGL(elr_kernel, dim3((NN + 3) / 4), b256, 0, stream, fs, attn_l, attn_r, el, er, NN);
    hipLaunchKernelGGL(scan1_kernel, dim3((NN + 255) / 256), b256, 0, stream, cnt, offs, blksum, NN);
    hipLaunchKernelGGL(scan2_kernel, dim3(1), b256, 0, stream, blksum, (NN + 255) / 256);
    hipLaunchKernelGGL(scan3_kernel, dim3((NN + 255) / 256), b256, 0, stream, offs, blksum, NN, NEDGE);
    hipLaunchKernelGGL(fillidx_kernel, dim3((NEDGE + 255) / 256), b256, 0, stream,
                       dst, src, mask, offs, cursor, es, NEDGE);
    hipLaunchKernelGGL(agg_kernel, dim3((NN + 3) / 4), b256, 0, stream,
                       offs, es, e_pro, el, er, attn_m, fs, out, NN);
}

// Round 12
// 262.126 us; speedup vs baseline: 1.4962x; 1.4962x over previous
//
#include <hip/hip_runtime.h>
#include <hip/hip_bf16.h>
#include <hip/hip_fp16.h>

#define NN 50000
#define NEDGE 800000
#define INDIM 256
#define NH 8
#define ND 32
#define HD 256
#define NT 4
#define NF 16

typedef __attribute__((ext_vector_type(8))) short s16x8;
typedef __attribute__((ext_vector_type(4))) float f32x4;
typedef unsigned short u16;

__device__ __forceinline__ float bf2f(u16 u) {
    return __uint_as_float(((unsigned int)u) << 16);
}
__device__ __forceinline__ u16 f2bf(float f) {
    __hip_bfloat16 h = __float2bfloat16(f);
    return *reinterpret_cast<u16*>(&h);
}
__device__ __forceinline__ u16 f2h(float f) {
    __half h = __float2half(f);
    return *reinterpret_cast<u16*>(&h);
}
__device__ __forceinline__ float h2f(u16 u) {
    __half h = *reinterpret_cast<__half*>(&u);
    return __half2float(h);
}

// ---------------- prep: W transpose->bf16  +  zero cnt/cursor
__global__ __launch_bounds__(256) void prep_kernel(const float* __restrict__ W,
                                                   u16* __restrict__ Wt,
                                                   int* __restrict__ cnt,
                                                   int* __restrict__ cursor)
{
    int idx = blockIdx.x * 256 + threadIdx.x;   // grid = 256 blocks -> 65536
    int k = idx >> 8, c = idx & 255;
    Wt[(size_t)c * 256 + k] = f2bf(W[idx]);
    if (idx < NN) { cnt[idx] = 0; cursor[idx] = 0; }
}

// ---------------- MFMA GEMM (+ dst histogram riding along)
__global__ __launch_bounds__(256) void gemm_mfma(
    const float* __restrict__ feat, const u16* __restrict__ Wt,
    const int* __restrict__ dst, int* __restrict__ cnt,
    u16* __restrict__ fs, int nrows)
{
    const int tid = threadIdx.x;
    {
        int e0 = (blockIdx.x * 256 + tid) * 2;
        if (e0 < NEDGE)     atomicAdd(&cnt[dst[e0]], 1);
        if (e0 + 1 < NEDGE) atomicAdd(&cnt[dst[e0 + 1]], 1);
    }

    __shared__ u16 At[32 * 256];   // 16 KB, swizzled
    const int brow = blockIdx.x * 32;

    #pragma unroll
    for (int it = 0; it < 4; ++it) {
        int fo = it * 2048 + tid * 8;
        int row = fo >> 8, col = fo & 255;
        int grow = brow + row;
        if (grow >= nrows) grow = nrows - 1;
        const float* gp = feat + (size_t)grow * 256 + col;
        float4 x = *reinterpret_cast<const float4*>(gp);
        float4 y = *reinterpret_cast<const float4*>(gp + 4);
        s16x8 v;
        v[0] = (short)f2bf(x.x); v[1] = (short)f2bf(x.y);
        v[2] = (short)f2bf(x.z); v[3] = (short)f2bf(x.w);
        v[4] = (short)f2bf(y.x); v[5] = (short)f2bf(y.y);
        v[6] = (short)f2bf(y.z); v[7] = (short)f2bf(y.w);
        int byte = (col * 2) ^ ((row & 7) << 4);
        *reinterpret_cast<s16x8*>((char*)At + row * 512 + byte) = v;
    }
    __syncthreads();

    const int wave = tid >> 6, lane = tid & 63;
    const int c0 = wave * 64;
    const int rA = lane & 15;
    const int kg = lane >> 4;

    f32x4 acc[2][4] = {};

    for (int k0 = 0; k0 < 256; k0 += 32) {
        const int kk = k0 + kg * 8;
        const int byte = (kk * 2) ^ ((rA & 7) << 4);
        s16x8 a0 = *reinterpret_cast<const s16x8*>((char*)At + rA * 512 + byte);
        s16x8 a1 = *reinterpret_cast<const s16x8*>((char*)At + (16 + rA) * 512 + byte);
        #pragma unroll
        for (int ct = 0; ct < 4; ++ct) {
            s16x8 b = *reinterpret_cast<const s16x8*>(Wt + (size_t)(c0 + ct * 16 + rA) * 256 + kk);
            acc[0][ct] = __builtin_amdgcn_mfma_f32_16x16x32_bf16(a0, b, acc[0][ct], 0, 0, 0);
            acc[1][ct] = __builtin_amdgcn_mfma_f32_16x16x32_bf16(a1, b, acc[1][ct], 0, 0, 0);
        }
    }

    #pragma unroll
    for (int rt = 0; rt < 2; ++rt) {
        #pragma unroll
        for (int r = 0; r < 4; ++r) {
            int row = brow + rt * 16 + kg * 4 + r;
            if (row < nrows) {
                #pragma unroll
                for (int ct = 0; ct < 4; ++ct) {
                    fs[(size_t)row * 256 + c0 + ct * 16 + rA] = f2bf(acc[rt][ct][r]);
                }
            }
        }
    }
}

// ---------------- el/er (f16): [N,H,T] = einsum(fs[n,h,d], attn_{l,r}[h,d,t])
__global__ __launch_bounds__(256) void elr_kernel(
    const u16* __restrict__ fs,
    const float* __restrict__ attn_l, const float* __restrict__ attn_r,
    u16* __restrict__ el, u16* __restrict__ er, int n)
{
    __shared__ float s_al[NH * ND * NT];
    __shared__ float s_ar[NH * ND * NT];
    for (int i = threadIdx.x; i < NH * ND * NT; i += 256) {
        s_al[i] = attn_l[i];
        s_ar[i] = attn_r[i];
    }
    __syncthreads();
    int wv = threadIdx.x >> 6, lane = threadIdx.x & 63;
    int node = blockIdx.x * 4 + wv;
    if (node >= n) return;
    int h = lane >> 3, j0 = (lane & 7) * 4;
    ushort4 u = *reinterpret_cast<const ushort4*>(fs + (size_t)node * HD + lane * 4);
    float f0 = bf2f(u.x), f1 = bf2f(u.y), f2 = bf2f(u.z), f3 = bf2f(u.w);
    const float* al = s_al + h * (ND * NT) + j0 * NT;
    const float* ar = s_ar + h * (ND * NT) + j0 * NT;
    float pl[NT], pr[NT];
    #pragma unroll
    for (int t = 0; t < NT; ++t) {
        pl[t] = f0*al[t] + f1*al[NT + t] + f2*al[2*NT + t] + f3*al[3*NT + t];
        pr[t] = f0*ar[t] + f1*ar[NT + t] + f2*ar[2*NT + t] + f3*ar[3*NT + t];
    }
    #pragma unroll
    for (int d = 1; d < 8; d <<= 1) {
        #pragma unroll
        for (int t = 0; t < NT; ++t) {
            pl[t] += __shfl_xor(pl[t], d);
            pr[t] += __shfl_xor(pr[t], d);
        }
    }
    if ((lane & 7) == 0) {
        ushort4 ol, orr;
        ol.x = f2h(pl[0]); ol.y = f2h(pl[1]); ol.z = f2h(pl[2]); ol.w = f2h(pl[3]);
        orr.x = f2h(pr[0]); orr.y = f2h(pr[1]); orr.z = f2h(pr[2]); orr.w = f2h(pr[3]);
        *reinterpret_cast<ushort4*>(el + (size_t)node * (NH*NT) + h * NT) = ol;
        *reinterpret_cast<ushort4*>(er + (size_t)node * (NH*NT) + h * NT) = orr;
    }
}

// ---------------- CSR scan
__global__ void scan1_kernel(const int* __restrict__ cnt, int* __restrict__ off,
                             int* __restrict__ blksum, int n) {
    __shared__ int sm[256];
    int i = blockIdx.x * 256 + threadIdx.x;
    int v = (i < n) ? cnt[i] : 0;
    sm[threadIdx.x] = v;
    __syncthreads();
    for (int d = 1; d < 256; d <<= 1) {
        int t = (threadIdx.x >= d) ? sm[threadIdx.x - d] : 0;
        __syncthreads();
        sm[threadIdx.x] += t;
        __syncthreads();
    }
    if (i < n) off[i] = sm[threadIdx.x] - v;
    if (threadIdx.x == 255) blksum[blockIdx.x] = sm[255];
}

__global__ void scan2_kernel(int* blksum, int nb) {
    __shared__ int sm[256];
    int v = (threadIdx.x < nb) ? blksum[threadIdx.x] : 0;
    sm[threadIdx.x] = v;
    __syncthreads();
    for (int d = 1; d < 256; d <<= 1) {
        int t = (threadIdx.x >= d) ? sm[threadIdx.x - d] : 0;
        __syncthreads();
        sm[threadIdx.x] += t;
        __syncthreads();
    }
    blksum[threadIdx.x] = sm[threadIdx.x] - v;
}

__global__ void scan3_kernel(int* __restrict__ off, const int* __restrict__ blksum,
                             int n, int ne) {
    int i = blockIdx.x * 256 + threadIdx.x;
    if (i < n) off[i] += blksum[blockIdx.x];
    if (i == 0) off[n] = ne;
}

// ---------------- fillidx: scatter es = int2(e, src). 8B/slot, dedicated kernel
// (scatter anti-composes with streaming work; standalone it runs at full occupancy).
__global__ void fillidx_kernel(const int* __restrict__ dst, const int* __restrict__ src,
                               const int* __restrict__ off, int* __restrict__ cursor,
                               int2* __restrict__ es, int ne) {
    int e = blockIdx.x * 256 + threadIdx.x;
    if (e < ne) {
        int d = dst[e];
        int p = atomicAdd(&cursor[d], 1);
        es[off[d] + p] = make_int2(e, src[e]);
    }
}

// ---------------- edge logits -> ev = exp(leaky(v)) f16, PURE STREAMING.
// 8 lanes per edge; lane j = head j. 32 edges per 256-thread block.
__global__ __launch_bounds__(256) void edge_kernel(
    const float* __restrict__ e_pro, const float* __restrict__ mask,
    const float* __restrict__ attn_m,
    const int* __restrict__ src, const int* __restrict__ dst,
    const u16* __restrict__ el, const u16* __restrict__ er,
    u16* __restrict__ ev, int ne)
{
    __shared__ float4 s_am4[NF][NH];   // [f][h] = attn_m[h][f][0..3]
    __shared__ float s_ep[32][17];
    __shared__ float s_mk[32][5];
    const int tid = threadIdx.x;
    const int eb = blockIdx.x * 32;
    const int j = tid & 7;      // head
    const int el_ = (tid >> 3) & 31;
    const int e = eb + (tid >> 3);

    // early gathers: latency drains under staging/compute
    int s = src[e], d = dst[e];
    union { uint2 v; u16 u[4]; } lv, rv;
    lv.v = *reinterpret_cast<const uint2*>(el + (size_t)s * (NH*NT) + j * NT);
    rv.v = *reinterpret_cast<const uint2*>(er + (size_t)d * (NH*NT) + j * NT);

    for (int i = tid; i < NH * NF; i += 256) {
        int h = i >> 4, f = i & 15;
        const float* p = attn_m + (size_t)h * (NF * NT) + f * NT;
        s_am4[f][h] = make_float4(p[0], p[1], p[2], p[3]);
    }
    {
        int f2i = tid * 2;
        float2 v = *reinterpret_cast<const float2*>(e_pro + (size_t)eb * NF + f2i);
        int e_l = f2i >> 4, f = f2i & 15;
        s_ep[e_l][f] = v.x; s_ep[e_l][f + 1] = v.y;
    }
    if (tid < 128) {
        s_mk[tid >> 2][tid & 3] = mask[(size_t)eb * NT + tid];
    }
    __syncthreads();

    float4 mk = make_float4(s_mk[el_][0], s_mk[el_][1], s_mk[el_][2], s_mk[el_][3]);

    float em = 0.f;
    #pragma unroll
    for (int f = 0; f < NF; ++f) {
        float4 am = s_am4[f][j];
        float amm = mk.x*am.x + mk.y*am.y + mk.z*am.z + mk.w*am.w;
        em = fmaf(s_ep[el_][f], amm, em);
    }
    float left  = mk.x*h2f(lv.u[0]) + mk.y*h2f(lv.u[1]) + mk.z*h2f(lv.u[2]) + mk.w*h2f(lv.u[3]);
    float right = mk.x*h2f(rv.u[0]) + mk.y*h2f(rv.u[1]) + mk.z*h2f(rv.u[2]) + mk.w*h2f(rv.u[3]);

    float v = (left + right + em) * (1.0f / 3.0f);
    v = v > 0.f ? v : 0.2f * v;
    ev[(size_t)e * NH + j] = f2h(__expf(v));   // coalesced
}

// ---------------- fused softmax-normalize + aggregation, one wave per dst node.
// Single pass: per-lane sw (= full per-head sum via shfl distribution);
// per chunk, 8 shfl pairs -> 8 hoisted row loads -> 32 FMA.
__global__ __launch_bounds__(256) void agg_kernel(
    const int* __restrict__ off, const int2* __restrict__ es,
    const u16* __restrict__ ev, const u16* __restrict__ fs,
    float* __restrict__ out, int n)
{
    int wv = threadIdx.x >> 6, lane = threadIdx.x & 63;
    int node = blockIdx.x * 4 + wv;
    if (node >= n) return;
    int beg = off[node], end = off[node + 1];
    int deg = end - beg;

    // register cache fill: lane = (sub<<3)|h holds (ev[e][h], src) for edge beg+slot*8+sub
    int h = lane & 7, sub = lane >> 3;
    float vc[8];
    int sc[8];
    #pragma unroll
    for (int slot = 0; slot < 8; ++slot) {
        int i = beg + slot * 8 + sub;
        float v = 0.f; int sn = 0;
        if (i < end) {
            int2 p = es[i];
            v = h2f(ev[(size_t)p.x * NH + h]);
            sn = p.y;
        }
        vc[slot] = v; sc[slot] = sn;
    }

    // main pass: lane owns cols lane*4..+3 for head h2 = lane>>3
    int h2 = lane >> 3;
    const int col = lane * 4;
    float a0 = 0.f, a1 = 0.f, a2 = 0.f, a3 = 0.f, sw = 0.f;
    int deg_ = deg < 64 ? deg : 64;
    int nchunk = (deg_ + 7) >> 3;
    #pragma unroll
    for (int c = 0; c < 8; ++c) {
        if (c >= nchunk) break;               // uniform
        float w8 = vc[c];
        int s8 = sc[c];
        float w[8]; int sn[8];
        #pragma unroll
        for (int q = 0; q < 8; ++q) {
            w[q]  = __shfl(w8, q * 8 + h2);
            sn[q] = __shfl(s8, q * 8 + h2);
        }
        ushort4 u[8];
        #pragma unroll
        for (int q = 0; q < 8; ++q)
            u[q] = *reinterpret_cast<const ushort4*>(fs + (size_t)sn[q] * HD + col);
        #pragma unroll
        for (int q = 0; q < 8; ++q) {         // padding: w=0, sn=0 -> no-op
            sw += w[q];
            a0 = fmaf(w[q], bf2f(u[q].x), a0);
            a1 = fmaf(w[q], bf2f(u[q].y), a1);
            a2 = fmaf(w[q], bf2f(u[q].z), a2);
            a3 = fmaf(w[q], bf2f(u[q].w), a3);
        }
    }
    for (int i = beg + 64; i < end; ++i) {    // rare deg>64 tail, single pass
        int2 p = es[i];
        float w = h2f(ev[(size_t)p.x * NH + h2]);
        sw += w;
        ushort4 u = *reinterpret_cast<const ushort4*>(fs + (size_t)p.y * HD + col);
        a0 = fmaf(w, bf2f(u.x), a0); a1 = fmaf(w, bf2f(u.y), a1);
        a2 = fmaf(w, bf2f(u.z), a2); a3 = fmaf(w, bf2f(u.w), a3);
    }
    float invS = sw > 0.f ? 1.f / sw : 0.f;
    a0 *= invS; a1 *= invS; a2 *= invS; a3 *= invS;
    *reinterpret_cast<float4*>(&out[(size_t)node * HD + col]) = make_float4(a0, a1, a2, a3);
}

extern "C" void kernel_launch(void* const* d_in, const int* in_sizes, int n_in,
                              void* d_out, int out_size, void* d_ws, size_t ws_size,
                              hipStream_t stream)
{
    const float* feat   = (const float*)d_in[0];
    const float* e_pro  = (const float*)d_in[1];
    const float* mask   = (const float*)d_in[2];
    const float* W_n    = (const float*)d_in[3];
    const float* attn_l = (const float*)d_in[4];
    const float* attn_r = (const float*)d_in[5];
    const float* attn_m = (const float*)d_in[6];
    const int* src      = (const int*)d_in[7];
    const int* dst      = (const int*)d_in[8];
    float* out = (float*)d_out;

    char* ws = (char*)d_ws;
    size_t o = 0;
    auto alloc = [&](size_t bytes) -> void* {
        void* p = (void*)(ws + o);
        o += (bytes + 255) & ~(size_t)255;
        return p;
    };
    u16* fs     = (u16*)alloc((size_t)NN * HD * 2);
    u16* Wt     = (u16*)alloc((size_t)INDIM * HD * 2);
    u16* el     = (u16*)alloc((size_t)NN * NH * NT * 2);
    u16* er     = (u16*)alloc((size_t)NN * NH * NT * 2);
    u16* ev     = (u16*)alloc((size_t)NEDGE * NH * 2);
    int2* es    = (int2*)alloc((size_t)NEDGE * 8);
    int* cnt    = (int*)alloc((size_t)NN * 4);
    int* cursor = (int*)alloc((size_t)NN * 4);
    int* offs   = (int*)alloc((size_t)(NN + 1) * 4);
    int* blksum = (int*)alloc(256 * 4);
    (void)ws_size; (void)in_sizes; (void)n_in; (void)out_size;

    dim3 b256(256);
    hipLaunchKernelGGL(prep_kernel, dim3(256), b256, 0, stream, W_n, Wt, cnt, cursor);
    hipLaunchKernelGGL(gemm_mfma, dim3((NN + 31) / 32), b256, 0, stream, feat, Wt, dst, cnt, fs, NN);
    hipLaunchKernelGGL(scan1_kernel, dim3((NN + 255) / 256), b256, 0, stream, cnt, offs, blksum, NN);
    hipLaunchKernelGGL(scan2_kernel, dim3(1), b256, 0, stream, blksum, (NN + 255) / 256);
    hipLaunchKernelGGL(scan3_kernel, dim3((NN + 255) / 256), b256, 0, stream, offs, blksum, NN, NEDGE);
    hipLaunchKernelGGL(fillidx_kernel, dim3((NEDGE + 255) / 256), b256, 0, stream,
                       dst, src, offs, cursor, es, NEDGE);
    hipLaunchKernelGGL(elr_kernel, dim3((NN + 3) / 4), b256, 0, stream, fs, attn_l, attn_r, el, er, NN);
    hipLaunchKernelGGL(edge_kernel, dim3(NEDGE / 32), b256, 0, stream,
                       e_pro, mask, attn_m, src, dst, el, er, ev, NEDGE);
    hipLaunchKernelGGL(agg_kernel, dim3((NN + 3) / 4), b256, 0, stream,
                       offs, es, ev, fs, out, NN);
}

// Round 13
// 230.978 us; speedup vs baseline: 1.6980x; 1.1349x over previous
//
#include <hip/hip_runtime.h>
#include <hip/hip_bf16.h>
#include <hip/hip_fp16.h>

#define NN 50000
#define NEDGE 800000
#define INDIM 256
#define NH 8
#define ND 32
#define HD 256
#define NT 4
#define NF 16

typedef __attribute__((ext_vector_type(8))) short s16x8;
typedef __attribute__((ext_vector_type(4))) float f32x4;
typedef unsigned short u16;

__device__ __forceinline__ float bf2f(u16 u) {
    return __uint_as_float(((unsigned int)u) << 16);
}
__device__ __forceinline__ u16 f2bf(float f) {
    __hip_bfloat16 h = __float2bfloat16(f);
    return *reinterpret_cast<u16*>(&h);
}
__device__ __forceinline__ u16 f2h(float f) {
    __half h = __float2half(f);
    return *reinterpret_cast<u16*>(&h);
}
__device__ __forceinline__ float h2f(u16 u) {
    __half h = *reinterpret_cast<__half*>(&u);
    return __half2float(h);
}

// ---------------- prep: W transpose->bf16  +  zero cnt/cursor
__global__ __launch_bounds__(256) void prep_kernel(const float* __restrict__ W,
                                                   u16* __restrict__ Wt,
                                                   int* __restrict__ cnt,
                                                   int* __restrict__ cursor)
{
    int idx = blockIdx.x * 256 + threadIdx.x;   // grid = 256 blocks -> 65536
    int k = idx >> 8, c = idx & 255;
    Wt[(size_t)c * 256 + k] = f2bf(W[idx]);
    if (idx < NN) { cnt[idx] = 0; cursor[idx] = 0; }
}

// ---------------- MFMA GEMM (+ dst histogram riding along)
__global__ __launch_bounds__(256) void gemm_mfma(
    const float* __restrict__ feat, const u16* __restrict__ Wt,
    const int* __restrict__ dst, int* __restrict__ cnt,
    u16* __restrict__ fs, int nrows)
{
    const int tid = threadIdx.x;
    {
        int e0 = (blockIdx.x * 256 + tid) * 2;
        if (e0 < NEDGE)     atomicAdd(&cnt[dst[e0]], 1);
        if (e0 + 1 < NEDGE) atomicAdd(&cnt[dst[e0 + 1]], 1);
    }

    __shared__ u16 At[32 * 256];   // 16 KB, swizzled
    const int brow = blockIdx.x * 32;

    #pragma unroll
    for (int it = 0; it < 4; ++it) {
        int fo = it * 2048 + tid * 8;
        int row = fo >> 8, col = fo & 255;
        int grow = brow + row;
        if (grow >= nrows) grow = nrows - 1;
        const float* gp = feat + (size_t)grow * 256 + col;
        float4 x = *reinterpret_cast<const float4*>(gp);
        float4 y = *reinterpret_cast<const float4*>(gp + 4);
        s16x8 v;
        v[0] = (short)f2bf(x.x); v[1] = (short)f2bf(x.y);
        v[2] = (short)f2bf(x.z); v[3] = (short)f2bf(x.w);
        v[4] = (short)f2bf(y.x); v[5] = (short)f2bf(y.y);
        v[6] = (short)f2bf(y.z); v[7] = (short)f2bf(y.w);
        int byte = (col * 2) ^ ((row & 7) << 4);
        *reinterpret_cast<s16x8*>((char*)At + row * 512 + byte) = v;
    }
    __syncthreads();

    const int wave = tid >> 6, lane = tid & 63;
    const int c0 = wave * 64;
    const int rA = lane & 15;
    const int kg = lane >> 4;

    f32x4 acc[2][4] = {};

    for (int k0 = 0; k0 < 256; k0 += 32) {
        const int kk = k0 + kg * 8;
        const int byte = (kk * 2) ^ ((rA & 7) << 4);
        s16x8 a0 = *reinterpret_cast<const s16x8*>((char*)At + rA * 512 + byte);
        s16x8 a1 = *reinterpret_cast<const s16x8*>((char*)At + (16 + rA) * 512 + byte);
        #pragma unroll
        for (int ct = 0; ct < 4; ++ct) {
            s16x8 b = *reinterpret_cast<const s16x8*>(Wt + (size_t)(c0 + ct * 16 + rA) * 256 + kk);
            acc[0][ct] = __builtin_amdgcn_mfma_f32_16x16x32_bf16(a0, b, acc[0][ct], 0, 0, 0);
            acc[1][ct] = __builtin_amdgcn_mfma_f32_16x16x32_bf16(a1, b, acc[1][ct], 0, 0, 0);
        }
    }

    #pragma unroll
    for (int rt = 0; rt < 2; ++rt) {
        #pragma unroll
        for (int r = 0; r < 4; ++r) {
            int row = brow + rt * 16 + kg * 4 + r;
            if (row < nrows) {
                #pragma unroll
                for (int ct = 0; ct < 4; ++ct) {
                    fs[(size_t)row * 256 + c0 + ct * 16 + rA] = f2bf(acc[rt][ct][r]);
                }
            }
        }
    }
}

// ---------------- el/er (f16): [N,H,T] = einsum(fs[n,h,d], attn_{l,r}[h,d,t])
__global__ __launch_bounds__(256) void elr_kernel(
    const u16* __restrict__ fs,
    const float* __restrict__ attn_l, const float* __restrict__ attn_r,
    u16* __restrict__ el, u16* __restrict__ er, int n)
{
    __shared__ float s_al[NH * ND * NT];
    __shared__ float s_ar[NH * ND * NT];
    for (int i = threadIdx.x; i < NH * ND * NT; i += 256) {
        s_al[i] = attn_l[i];
        s_ar[i] = attn_r[i];
    }
    __syncthreads();
    int wv = threadIdx.x >> 6, lane = threadIdx.x & 63;
    int node = blockIdx.x * 4 + wv;
    if (node >= n) return;
    int h = lane >> 3, j0 = (lane & 7) * 4;
    ushort4 u = *reinterpret_cast<const ushort4*>(fs + (size_t)node * HD + lane * 4);
    float f0 = bf2f(u.x), f1 = bf2f(u.y), f2 = bf2f(u.z), f3 = bf2f(u.w);
    const float* al = s_al + h * (ND * NT) + j0 * NT;
    const float* ar = s_ar + h * (ND * NT) + j0 * NT;
    float pl[NT], pr[NT];
    #pragma unroll
    for (int t = 0; t < NT; ++t) {
        pl[t] = f0*al[t] + f1*al[NT + t] + f2*al[2*NT + t] + f3*al[3*NT + t];
        pr[t] = f0*ar[t] + f1*ar[NT + t] + f2*ar[2*NT + t] + f3*ar[3*NT + t];
    }
    #pragma unroll
    for (int d = 1; d < 8; d <<= 1) {
        #pragma unroll
        for (int t = 0; t < NT; ++t) {
            pl[t] += __shfl_xor(pl[t], d);
            pr[t] += __shfl_xor(pr[t], d);
        }
    }
    if ((lane & 7) == 0) {
        ushort4 ol, orr;
        ol.x = f2h(pl[0]); ol.y = f2h(pl[1]); ol.z = f2h(pl[2]); ol.w = f2h(pl[3]);
        orr.x = f2h(pr[0]); orr.y = f2h(pr[1]); orr.z = f2h(pr[2]); orr.w = f2h(pr[3]);
        *reinterpret_cast<ushort4*>(el + (size_t)node * (NH*NT) + h * NT) = ol;
        *reinterpret_cast<ushort4*>(er + (size_t)node * (NH*NT) + h * NT) = orr;
    }
}

// ---------------- CSR scan
__global__ void scan1_kernel(const int* __restrict__ cnt, int* __restrict__ off,
                             int* __restrict__ blksum, int n) {
    __shared__ int sm[256];
    int i = blockIdx.x * 256 + threadIdx.x;
    int v = (i < n) ? cnt[i] : 0;
    sm[threadIdx.x] = v;
    __syncthreads();
    for (int d = 1; d < 256; d <<= 1) {
        int t = (threadIdx.x >= d) ? sm[threadIdx.x - d] : 0;
        __syncthreads();
        sm[threadIdx.x] += t;
        __syncthreads();
    }
    if (i < n) off[i] = sm[threadIdx.x] - v;
    if (threadIdx.x == 255) blksum[blockIdx.x] = sm[255];
}

__global__ void scan2_kernel(int* blksum, int nb) {
    __shared__ int sm[256];
    int v = (threadIdx.x < nb) ? blksum[threadIdx.x] : 0;
    sm[threadIdx.x] = v;
    __syncthreads();
    for (int d = 1; d < 256; d <<= 1) {
        int t = (threadIdx.x >= d) ? sm[threadIdx.x - d] : 0;
        __syncthreads();
        sm[threadIdx.x] += t;
        __syncthreads();
    }
    blksum[threadIdx.x] = sm[threadIdx.x] - v;
}

__global__ void scan3_kernel(int* __restrict__ off, const int* __restrict__ blksum,
                             int n, int ne) {
    int i = blockIdx.x * 256 + threadIdx.x;
    if (i < n) off[i] += blksum[blockIdx.x];
    if (i == 0) off[n] = ne;
}

// ---------------- BLOCK-FUSED fill + edge kernel.
// Grid = 9*3125 = 28125 blocks. blockIdx%9==0 -> fill path (256 edges, es scatter);
// else -> streaming edge-logit path (32 edges). Scatter blocks stall on random-line
// RMW while stream blocks keep the VALU fed; CU scheduler overlaps them.
__global__ __launch_bounds__(256) void fill_edge_kernel(
    const float* __restrict__ e_pro, const float* __restrict__ mask,
    const float* __restrict__ attn_m,
    const int* __restrict__ src, const int* __restrict__ dst,
    const u16* __restrict__ el, const u16* __restrict__ er,
    const int* __restrict__ off, int* __restrict__ cursor,
    int2* __restrict__ es, u16* __restrict__ ev, int ne)
{
    const int bid = blockIdx.x;
    const int tid = threadIdx.x;

    if (bid % 9 == 0) {
        // ---- fill path: scatter es = int2(e, src)
        int e = (bid / 9) * 256 + tid;
        if (e < ne) {
            int d = dst[e];
            int p = atomicAdd(&cursor[d], 1);
            es[off[d] + p] = make_int2(e, src[e]);
        }
        return;
    }

    // ---- streaming edge path: ebid in 0..24999
    const int ebid = bid - 1 - bid / 9;
    __shared__ float4 s_am4[NF][NH];   // [f][h] = attn_m[h][f][0..3]
    __shared__ float s_ep[32][17];
    __shared__ float s_mk[32][5];
    const int eb = ebid * 32;
    const int j = tid & 7;      // head
    const int el_ = (tid >> 3) & 31;
    const int e = eb + (tid >> 3);

    // early gathers: latency drains under staging/compute
    int s = src[e], d = dst[e];
    union { uint2 v; u16 u[4]; } lv, rv;
    lv.v = *reinterpret_cast<const uint2*>(el + (size_t)s * (NH*NT) + j * NT);
    rv.v = *reinterpret_cast<const uint2*>(er + (size_t)d * (NH*NT) + j * NT);

    for (int i = tid; i < NH * NF; i += 256) {
        int h = i >> 4, f = i & 15;
        const float* p = attn_m + (size_t)h * (NF * NT) + f * NT;
        s_am4[f][h] = make_float4(p[0], p[1], p[2], p[3]);
    }
    {
        int f2i = tid * 2;
        float2 v = *reinterpret_cast<const float2*>(e_pro + (size_t)eb * NF + f2i);
        int e_l = f2i >> 4, f = f2i & 15;
        s_ep[e_l][f] = v.x; s_ep[e_l][f + 1] = v.y;
    }
    if (tid < 128) {
        s_mk[tid >> 2][tid & 3] = mask[(size_t)eb * NT + tid];
    }
    __syncthreads();

    float4 mk = make_float4(s_mk[el_][0], s_mk[el_][1], s_mk[el_][2], s_mk[el_][3]);

    float em = 0.f;
    #pragma unroll
    for (int f = 0; f < NF; ++f) {
        float4 am = s_am4[f][j];
        float amm = mk.x*am.x + mk.y*am.y + mk.z*am.z + mk.w*am.w;
        em = fmaf(s_ep[el_][f], amm, em);
    }
    float left  = mk.x*h2f(lv.u[0]) + mk.y*h2f(lv.u[1]) + mk.z*h2f(lv.u[2]) + mk.w*h2f(lv.u[3]);
    float right = mk.x*h2f(rv.u[0]) + mk.y*h2f(rv.u[1]) + mk.z*h2f(rv.u[2]) + mk.w*h2f(rv.u[3]);

    float v = (left + right + em) * (1.0f / 3.0f);
    v = v > 0.f ? v : 0.2f * v;
    ev[(size_t)e * NH + j] = f2h(__expf(v));   // coalesced
}

// ---------------- fused softmax-normalize + aggregation, one wave per dst node.
// Single pass: per-lane sw (= full per-head sum via shfl distribution);
// per chunk, 8 shfl pairs -> 8 hoisted row loads -> 32 FMA.
__global__ __launch_bounds__(256) void agg_kernel(
    const int* __restrict__ off, const int2* __restrict__ es,
    const u16* __restrict__ ev, const u16* __restrict__ fs,
    float* __restrict__ out, int n)
{
    int wv = threadIdx.x >> 6, lane = threadIdx.x & 63;
    int node = blockIdx.x * 4 + wv;
    if (node >= n) return;
    int beg = off[node], end = off[node + 1];
    int deg = end - beg;

    // register cache fill: lane = (sub<<3)|h holds (ev[e][h], src) for edge beg+slot*8+sub
    int h = lane & 7, sub = lane >> 3;
    float vc[8];
    int sc[8];
    #pragma unroll
    for (int slot = 0; slot < 8; ++slot) {
        int i = beg + slot * 8 + sub;
        float v = 0.f; int sn = 0;
        if (i < end) {
            int2 p = es[i];
            v = h2f(ev[(size_t)p.x * NH + h]);
            sn = p.y;
        }
        vc[slot] = v; sc[slot] = sn;
    }

    // main pass: lane owns cols lane*4..+3 for head h2 = lane>>3
    int h2 = lane >> 3;
    const int col = lane * 4;
    float a0 = 0.f, a1 = 0.f, a2 = 0.f, a3 = 0.f, sw = 0.f;
    int deg_ = deg < 64 ? deg : 64;
    int nchunk = (deg_ + 7) >> 3;
    #pragma unroll
    for (int c = 0; c < 8; ++c) {
        if (c >= nchunk) break;               // uniform
        float w8 = vc[c];
        int s8 = sc[c];
        float w[8]; int sn[8];
        #pragma unroll
        for (int q = 0; q < 8; ++q) {
            w[q]  = __shfl(w8, q * 8 + h2);
            sn[q] = __shfl(s8, q * 8 + h2);
        }
        ushort4 u[8];
        #pragma unroll
        for (int q = 0; q < 8; ++q)
            u[q] = *reinterpret_cast<const ushort4*>(fs + (size_t)sn[q] * HD + col);
        #pragma unroll
        for (int q = 0; q < 8; ++q) {         // padding: w=0, sn=0 -> no-op
            sw += w[q];
            a0 = fmaf(w[q], bf2f(u[q].x), a0);
            a1 = fmaf(w[q], bf2f(u[q].y), a1);
            a2 = fmaf(w[q], bf2f(u[q].z), a2);
            a3 = fmaf(w[q], bf2f(u[q].w), a3);
        }
    }
    for (int i = beg + 64; i < end; ++i) {    // rare deg>64 tail, single pass
        int2 p = es[i];
        float w = h2f(ev[(size_t)p.x * NH + h2]);
        sw += w;
        ushort4 u = *reinterpret_cast<const ushort4*>(fs + (size_t)p.y * HD + col);
        a0 = fmaf(w, bf2f(u.x), a0); a1 = fmaf(w, bf2f(u.y), a1);
        a2 = fmaf(w, bf2f(u.z), a2); a3 = fmaf(w, bf2f(u.w), a3);
    }
    float invS = sw > 0.f ? 1.f / sw : 0.f;
    a0 *= invS; a1 *= invS; a2 *= invS; a3 *= invS;
    *reinterpret_cast<float4*>(&out[(size_t)node * HD + col]) = make_float4(a0, a1, a2, a3);
}

extern "C" void kernel_launch(void* const* d_in, const int* in_sizes, int n_in,
                              void* d_out, int out_size, void* d_ws, size_t ws_size,
                              hipStream_t stream)
{
    const float* feat   = (const float*)d_in[0];
    const float* e_pro  = (const float*)d_in[1];
    const float* mask   = (const float*)d_in[2];
    const float* W_n    = (const float*)d_in[3];
    const float* attn_l = (const float*)d_in[4];
    const float* attn_r = (const float*)d_in[5];
    const float* attn_m = (const float*)d_in[6];
    const int* src      = (const int*)d_in[7];
    const int* dst      = (const int*)d_in[8];
    float* out = (float*)d_out;

    char* ws = (char*)d_ws;
    size_t o = 0;
    auto alloc = [&](size_t bytes) -> void* {
        void* p = (void*)(ws + o);
        o += (bytes + 255) & ~(size_t)255;
        return p;
    };
    u16* fs     = (u16*)alloc((size_t)NN * HD * 2);
    u16* Wt     = (u16*)alloc((size_t)INDIM * HD * 2);
    u16* el     = (u16*)alloc((size_t)NN * NH * NT * 2);
    u16* er     = (u16*)alloc((size_t)NN * NH * NT * 2);
    u16* ev     = (u16*)alloc((size_t)NEDGE * NH * 2);
    int2* es    = (int2*)alloc((size_t)NEDGE * 8);
    int* cnt    = (int*)alloc((size_t)NN * 4);
    int* cursor = (int*)alloc((size_t)NN * 4);
    int* offs   = (int*)alloc((size_t)(NN + 1) * 4);
    int* blksum = (int*)alloc(256 * 4);
    (void)ws_size; (void)in_sizes; (void)n_in; (void)out_size;

    dim3 b256(256);
    hipLaunchKernelGGL(prep_kernel, dim3(256), b256, 0, stream, W_n, Wt, cnt, cursor);
    hipLaunchKernelGGL(gemm_mfma, dim3((NN + 31) / 32), b256, 0, stream, feat, Wt, dst, cnt, fs, NN);
    hipLaunchKernelGGL(elr_kernel, dim3((NN + 3) / 4), b256, 0, stream, fs, attn_l, attn_r, el, er, NN);
    hipLaunchKernelGGL(scan1_kernel, dim3((NN + 255) / 256), b256, 0, stream, cnt, offs, blksum, NN);
    hipLaunchKernelGGL(scan2_kernel, dim3(1), b256, 0, stream, blksum, (NN + 255) / 256);
    hipLaunchKernelGGL(scan3_kernel, dim3((NN + 255) / 256), b256, 0, stream, offs, blksum, NN, NEDGE);
    hipLaunchKernelGGL(fill_edge_kernel, dim3(9 * 3125), b256, 0, stream,
                       e_pro, mask, attn_m, src, dst, el, er, offs, cursor, es, ev, NEDGE);
    hipLaunchKernelGGL(agg_kernel, dim3((NN + 3) / 4), b256, 0, stream,
                       offs, es, ev, fs, out, NN);
}